// Round 3
// baseline (611.378 us; speedup 1.0000x reference)
//
#include <hip/hip_runtime.h>

// LSTM-GCN single step from (H=0, C=0).
// Collapsed math: Fg gate dead (C_prev=0), cheb(H,..)=bh, peephole wc[0],wc[1] dead.
//
// R7: R6's "depth-8 pipeline" never materialized (VGPR=20 proves the compiler
// re-serialized it: the per-element `if (idx < re)` guards are divergent within
// the wave -> exec-mask branches around every load -> loads sunk next to uses,
// one dependent rec->x chain per group, 303 us latency-bound at 313 GB/s).
// Fix: branch-free pipeline. Clamped indices (cndmask, loads unconditional),
// zeroed nrm for tail records, per-wave contiguous chunks, 2 records/step x
// UNR=8 steps with statically-indexed register arrays.

#define FDIM 32
#define MAX_N 100000
#define MAX_E 1600000
#define CBSH 6                                // 64 nodes per coarse bucket
#define CB 64
#define MAX_NB ((MAX_N + CB - 1) / CB)        // 1563 buckets max
#define NBLK 512                              // blocks in each edge pass
#define SCAN_TILE 1024                        // elements per scan block (256 thr x 4)
#define UNR 8                                 // record pairs in flight per wave

__device__ float g_deg[MAX_N];                // degree -> dinv in place
__device__ int   g_part[MAX_NB * NBLK + 1];   // per-(bin,block) counts -> offsets
__device__ int   g_blk[1024];                 // scan block sums
__device__ uint2 g_rec[MAX_E];                // packed {src<<6|dst_low, nrm} by bucket
__device__ float g_tx1[MAX_N * FDIM];         // L_hat @ x

__global__ void zero_kernel(int n_nodes, int nbuck) {
    int i = blockIdx.x * blockDim.x + threadIdx.x;
    for (; i < n_nodes; i += gridDim.x * blockDim.x) g_deg[i] = 0.f;
    if (blockIdx.x == 0 && threadIdx.x == 0) g_part[nbuck * NBLK] = 0;  // scan sentinel
}

// One edge pass: deg[s] += w (global f32 atomic, fire-and-forget, self-loops
// excluded) and LDS coarse histogram of dst>>6, flushed NON-atomically to
// g_part[bin*NBLK + block].
__global__ __launch_bounds__(256) void hist_deg_kernel(const int* __restrict__ ei,
                                                       const float* __restrict__ w,
                                                       int E, int n_nodes, int nbuck,
                                                       int per_blk) {
    __shared__ int h[MAX_NB];
    for (int i = threadIdx.x; i < nbuck; i += 256) h[i] = 0;
    __syncthreads();
    int start = blockIdx.x * per_blk;
    int end = start + per_blk;
    if (end > E) end = E;
    for (int e = start + threadIdx.x; e < end; e += 256) {
        int s = ei[e];
        int d = ei[E + e];
        if ((unsigned)s >= (unsigned)n_nodes || (unsigned)d >= (unsigned)n_nodes) continue;
        if (s != d) unsafeAtomicAdd(&g_deg[s], w[e]);
        atomicAdd(&h[d >> CBSH], 1);          // LDS atomic
    }
    __syncthreads();
    for (int i = threadIdx.x; i < nbuck; i += 256)
        g_part[i * NBLK + blockIdx.x] = h[i]; // plain store, no atomics
}

__global__ void dinv_kernel(int n) {
    int i = blockIdx.x * blockDim.x + threadIdx.x;
    if (i >= n) return;
    float d = g_deg[i];
    g_deg[i] = (d > 0.f) ? rsqrtf(d) : 0.f;
}

// --- exclusive scan over g_part[0..n), 3 kernels (n = nbuck*NBLK + 1 <= ~800k) ---
__global__ __launch_bounds__(256) void scan1_kernel(int n) {
    __shared__ int sh[256];
    int tid = threadIdx.x;
    int base = blockIdx.x * SCAN_TILE + tid * 4;
    int v[4];
#pragma unroll
    for (int i = 0; i < 4; ++i) v[i] = (base + i < n) ? g_part[base + i] : 0;
    int tsum = v[0] + v[1] + v[2] + v[3];
    sh[tid] = tsum;
    __syncthreads();
    for (int off = 1; off < 256; off <<= 1) {
        int t = (tid >= off) ? sh[tid - off] : 0;
        __syncthreads();
        sh[tid] += t;
        __syncthreads();
    }
    if (tid == 255) g_blk[blockIdx.x] = sh[255];
    int run = sh[tid] - tsum;   // exclusive offset within block
#pragma unroll
    for (int i = 0; i < 4; ++i) {
        if (base + i < n) g_part[base + i] = run;
        run += v[i];
    }
}

__global__ __launch_bounds__(256) void scan2_kernel(int nb) {   // nb <= 1024
    __shared__ int sh[256];
    int tid = threadIdx.x;
    int base = tid * 4;
    int v[4];
#pragma unroll
    for (int i = 0; i < 4; ++i) v[i] = (base + i < nb) ? g_blk[base + i] : 0;
    int tsum = v[0] + v[1] + v[2] + v[3];
    sh[tid] = tsum;
    __syncthreads();
    for (int off = 1; off < 256; off <<= 1) {
        int t = (tid >= off) ? sh[tid - off] : 0;
        __syncthreads();
        sh[tid] += t;
        __syncthreads();
    }
    int run = sh[tid] - tsum;
#pragma unroll
    for (int i = 0; i < 4; ++i) {
        if (base + i < nb) g_blk[base + i] = run;
        run += v[i];
    }
}

__global__ void scan3_kernel(int n) {
    int off = g_blk[blockIdx.x];
    int base = blockIdx.x * SCAN_TILE + threadIdx.x * 4;
#pragma unroll
    for (int i = 0; i < 4; ++i) {
        int idx = base + i;
        if (idx < n) g_part[idx] += off;
    }
}

// Re-reads the IDENTICAL edge range as hist_deg_kernel; per-bin LDS cursors start
// at the scanned (bin,block) offsets, so record placement needs no global atomics.
__global__ __launch_bounds__(256) void scatter_kernel(const int* __restrict__ ei,
                                                      const float* __restrict__ w,
                                                      int E, int n_nodes, int nbuck,
                                                      int per_blk) {
    __shared__ int cur[MAX_NB];
    for (int i = threadIdx.x; i < nbuck; i += 256)
        cur[i] = g_part[i * NBLK + blockIdx.x];
    __syncthreads();
    int start = blockIdx.x * per_blk;
    int end = start + per_blk;
    if (end > E) end = E;
    for (int e = start + threadIdx.x; e < end; e += 256) {
        int s = ei[e];
        int d = ei[E + e];
        if ((unsigned)s >= (unsigned)n_nodes || (unsigned)d >= (unsigned)n_nodes) continue;
        float nrm = (s == d) ? 0.f : -g_deg[s] * w[e] * g_deg[d];  // g_deg holds dinv
        int pos = atomicAdd(&cur[d >> CBSH], 1);                   // LDS atomic
        g_rec[pos] = make_uint2(((unsigned)s << CBSH) | (unsigned)(d & (CB - 1)),
                                __float_as_uint(nrm));
    }
}

// One block per 64-node bucket: accumulate tx1 rows in an 8 KB LDS tile with
// ds_add_f32 (lane f -> bank f, 2-way within wave = free), coalesced write-out.
// Branch-free register pipeline: each wave owns a contiguous chunk of the bucket's
// records; per iteration, 2 records/step x UNR=8 steps are loaded with CLAMPED
// indices (no divergent branches -> loads stay hoisted and independent), tail
// records contribute 0 via a zeroed nrm.
__global__ __launch_bounds__(256) void bucket_gather_kernel(const float* __restrict__ x,
                                                            int n_nodes, int nbuck) {
    __shared__ float acc[CB * FDIM];   // 8 KB
    int b = blockIdx.x;
    for (int i = threadIdx.x; i < CB * FDIM; i += 256) acc[i] = 0.f;
    int rs = g_part[b * NBLK];
    int re = g_part[(b + 1) * NBLK];   // b == nbuck-1 hits the sentinel (= total)
    __syncthreads();

    int wid  = __builtin_amdgcn_readfirstlane(threadIdx.x >> 6);  // 0..3, SGPR
    int half = (threadIdx.x >> 5) & 1;   // which record of each pair
    int f    = threadIdx.x & 31;

    int total = re - rs;
    int chunk = (total + 3) >> 2;        // per-wave contiguous range
    int wbeg = rs + wid * chunk;
    int wend = wbeg + chunk; if (wend > re) wend = re;

    for (int i0 = wbeg; i0 < wend; i0 += 2 * UNR) {
        uint2 r[UNR];
        float xv[UNR];
#pragma unroll
        for (int u = 0; u < UNR; ++u) {
            int idx = i0 + 2 * u + half;
            uint2 t = g_rec[(idx < wend) ? idx : wbeg];   // unconditional load
            t.y = (idx < wend) ? t.y : 0u;                // tail contributes 0
            r[u] = t;
        }
#pragma unroll
        for (int u = 0; u < UNR; ++u)
            xv[u] = x[(r[u].x >> CBSH) * FDIM + f];       // unconditional load
#pragma unroll
        for (int u = 0; u < UNR; ++u)
            atomicAdd(&acc[(r[u].x & (CB - 1)) * FDIM + f],
                      __uint_as_float(r[u].y) * xv[u]);
    }
    __syncthreads();
    int base = b << CBSH;
    for (int row = threadIdx.x >> 5; row < CB; row += 8) {
        int n = base + row;
        if (n < n_nodes) g_tx1[n * FDIM + f] = acc[row * FDIM + f];
    }
}

// 8 nodes per 256-thread block; thread (node, j) computes output feature j of
// gates i, c, o. Weights for the 3 live gates staged in LDS (24 KB).
__global__ __launch_bounds__(256) void gates_kernel(
    const float* __restrict__ x,
    const float* __restrict__ Wx, const float* __restrict__ bx,
    const float* __restrict__ bh, const float* __restrict__ wc,
    const float* __restrict__ bg, const float* __restrict__ lin_w,
    const float* __restrict__ lin_b, float* __restrict__ out, int n_nodes) {
    __shared__ float Ws[3 * 2048];      // gates {i,c,o} x K=2 x 32x32
    __shared__ float xs[8 * FDIM];
    __shared__ float ts[8 * FDIM];

    for (int idx = threadIdx.x; idx < 2048; idx += 256) {
        Ws[idx]          = Wx[0 * 2048 + idx];
        Ws[2048 + idx]   = Wx[2 * 2048 + idx];
        Ws[4096 + idx]   = Wx[3 * 2048 + idx];
    }
    int node0 = blockIdx.x * 8;
    {
        int n = node0 + (threadIdx.x >> 5);
        int f = threadIdx.x & 31;
        if (n < n_nodes) {
            xs[threadIdx.x] = x[n * FDIM + f];
            ts[threadIdx.x] = g_tx1[n * FDIM + f];
        }
    }
    __syncthreads();

    int ln = threadIdx.x >> 5;
    int j  = threadIdx.x & 31;
    int n  = node0 + ln;
    if (n >= n_nodes) return;

    const float* xr = &xs[ln * FDIM];
    const float* tr = &ts[ln * FDIM];
    float acc_i = 0.f, acc_c = 0.f, acc_o = 0.f;
#pragma unroll
    for (int k = 0; k < 32; ++k) {
        float xv = xr[k], tv = tr[k];
        int o0 = k * 32 + j;
        acc_i += xv * Ws[o0]          + tv * Ws[1024 + o0];
        acc_c += xv * Ws[2048 + o0]   + tv * Ws[3072 + o0];
        acc_o += xv * Ws[4096 + o0]   + tv * Ws[5120 + o0];
    }
    float bi = bx[0 * 32 + j] + bh[0 * 32 + j] + bg[0 * 32 + j];
    float bc = bx[2 * 32 + j] + bh[2 * 32 + j] + bg[2 * 32 + j];
    float bo = bx[3 * 32 + j] + bh[3 * 32 + j] + bg[3 * 32 + j];

    float I = 1.f / (1.f + __expf(-(acc_i + bi)));
    float T = tanhf(acc_c + bc);
    float C = I * T;                                    // Fg*C_prev = 0
    float O = 1.f / (1.f + __expf(-(acc_o + bo + wc[2 * 32 + j] * C)));
    float H = O * tanhf(C);
    float r = fmaxf(H, 0.f) * lin_w[j];
#pragma unroll
    for (int m = 16; m > 0; m >>= 1) r += __shfl_xor(r, m, 32);
    if (j == 0) out[n] = r + lin_b[0];
}

extern "C" void kernel_launch(void* const* d_in, const int* in_sizes, int n_in,
                              void* d_out, int out_size, void* d_ws, size_t ws_size,
                              hipStream_t stream) {
    const float* x     = (const float*)d_in[0];
    const int*   ei    = (const int*)d_in[1];      // int32 on device
    const float* w     = (const float*)d_in[2];
    const float* Wx    = (const float*)d_in[3];
    const float* bx    = (const float*)d_in[4];
    // d_in[5] = Wh: unused (H=0)
    const float* bh    = (const float*)d_in[6];
    const float* wc    = (const float*)d_in[7];
    const float* bg    = (const float*)d_in[8];
    const float* lin_w = (const float*)d_in[9];
    const float* lin_b = (const float*)d_in[10];
    float*       out   = (float*)d_out;

    int n_nodes = in_sizes[0] / FDIM;
    if (n_nodes > MAX_N) n_nodes = MAX_N;
    int E = in_sizes[2];
    if (E > MAX_E) E = MAX_E;

    int nbuck   = (n_nodes + CB - 1) >> CBSH;            // 1563 for N=100k
    int per_blk = (E + NBLK - 1) / NBLK;                 // 3125 edges/block
    int n_scan  = nbuck * NBLK + 1;                      // 800257
    int nb_scan = (n_scan + SCAN_TILE - 1) / SCAN_TILE;  // 782 (<= 1024 for scan2)

    zero_kernel<<<512, 256, 0, stream>>>(n_nodes, nbuck);
    hist_deg_kernel<<<NBLK, 256, 0, stream>>>(ei, w, E, n_nodes, nbuck, per_blk);
    dinv_kernel<<<(n_nodes + 255) / 256, 256, 0, stream>>>(n_nodes);
    scan1_kernel<<<nb_scan, 256, 0, stream>>>(n_scan);
    scan2_kernel<<<1, 256, 0, stream>>>(nb_scan);
    scan3_kernel<<<nb_scan, 256, 0, stream>>>(n_scan);
    scatter_kernel<<<NBLK, 256, 0, stream>>>(ei, w, E, n_nodes, nbuck, per_blk);
    bucket_gather_kernel<<<nbuck, 256, 0, stream>>>(x, n_nodes, nbuck);
    gates_kernel<<<(n_nodes + 7) / 8, 256, 0, stream>>>(
        x, Wx, bx, bh, wc, bg, lin_w, lin_b, out, n_nodes);
}

// Round 4
// 601.930 us; speedup vs baseline: 1.0157x; 1.0157x over previous
//
#include <hip/hip_runtime.h>

// LSTM-GCN single step from (H=0, C=0).
// Collapsed math: Fg gate dead (C_prev=0), cheb(H,..)=bh, peephole wc[0],wc[1] dead.
//
// R8: R6/R7's pipelines never materialized (VGPR=20 both times, 313 us flat).
// Root cause per rule #20: payload held in small ARRAYS (r[UNR], xv[UNR]) ->
// compiler re-rolled the phases into one rec->x->atomic chain per record.
// R4's gather DID pipeline and its shape was: guard-free main loop + NAMED
// scalars. This round: 16 records per wave iteration, named r0..r7/x0..x7,
// no guards in the main body (wave-uniform trip count), divergent scalar tail.

#define FDIM 32
#define MAX_N 100000
#define MAX_E 1600000
#define CBSH 6                                // 64 nodes per coarse bucket
#define CB 64
#define MAX_NB ((MAX_N + CB - 1) / CB)        // 1563 buckets max
#define NBLK 512                              // blocks in each edge pass
#define SCAN_TILE 1024                        // elements per scan block (256 thr x 4)

__device__ float g_deg[MAX_N];                // degree -> dinv in place
__device__ int   g_part[MAX_NB * NBLK + 1];   // per-(bin,block) counts -> offsets
__device__ int   g_blk[1024];                 // scan block sums
__device__ uint2 g_rec[MAX_E];                // packed {src<<6|dst_low, nrm} by bucket
__device__ float g_tx1[MAX_N * FDIM];         // L_hat @ x

__global__ void zero_kernel(int n_nodes, int nbuck) {
    int i = blockIdx.x * blockDim.x + threadIdx.x;
    for (; i < n_nodes; i += gridDim.x * blockDim.x) g_deg[i] = 0.f;
    if (blockIdx.x == 0 && threadIdx.x == 0) g_part[nbuck * NBLK] = 0;  // scan sentinel
}

// One edge pass: deg[s] += w (global f32 atomic, fire-and-forget, self-loops
// excluded) and LDS coarse histogram of dst>>6, flushed NON-atomically to
// g_part[bin*NBLK + block].
__global__ __launch_bounds__(256) void hist_deg_kernel(const int* __restrict__ ei,
                                                       const float* __restrict__ w,
                                                       int E, int n_nodes, int nbuck,
                                                       int per_blk) {
    __shared__ int h[MAX_NB];
    for (int i = threadIdx.x; i < nbuck; i += 256) h[i] = 0;
    __syncthreads();
    int start = blockIdx.x * per_blk;
    int end = start + per_blk;
    if (end > E) end = E;
    for (int e = start + threadIdx.x; e < end; e += 256) {
        int s = ei[e];
        int d = ei[E + e];
        if ((unsigned)s >= (unsigned)n_nodes || (unsigned)d >= (unsigned)n_nodes) continue;
        if (s != d) unsafeAtomicAdd(&g_deg[s], w[e]);
        atomicAdd(&h[d >> CBSH], 1);          // LDS atomic
    }
    __syncthreads();
    for (int i = threadIdx.x; i < nbuck; i += 256)
        g_part[i * NBLK + blockIdx.x] = h[i]; // plain store, no atomics
}

__global__ void dinv_kernel(int n) {
    int i = blockIdx.x * blockDim.x + threadIdx.x;
    if (i >= n) return;
    float d = g_deg[i];
    g_deg[i] = (d > 0.f) ? rsqrtf(d) : 0.f;
}

// --- exclusive scan over g_part[0..n), 3 kernels (n = nbuck*NBLK + 1 <= ~800k) ---
__global__ __launch_bounds__(256) void scan1_kernel(int n) {
    __shared__ int sh[256];
    int tid = threadIdx.x;
    int base = blockIdx.x * SCAN_TILE + tid * 4;
    int v[4];
#pragma unroll
    for (int i = 0; i < 4; ++i) v[i] = (base + i < n) ? g_part[base + i] : 0;
    int tsum = v[0] + v[1] + v[2] + v[3];
    sh[tid] = tsum;
    __syncthreads();
    for (int off = 1; off < 256; off <<= 1) {
        int t = (tid >= off) ? sh[tid - off] : 0;
        __syncthreads();
        sh[tid] += t;
        __syncthreads();
    }
    if (tid == 255) g_blk[blockIdx.x] = sh[255];
    int run = sh[tid] - tsum;   // exclusive offset within block
#pragma unroll
    for (int i = 0; i < 4; ++i) {
        if (base + i < n) g_part[base + i] = run;
        run += v[i];
    }
}

__global__ __launch_bounds__(256) void scan2_kernel(int nb) {   // nb <= 1024
    __shared__ int sh[256];
    int tid = threadIdx.x;
    int base = tid * 4;
    int v[4];
#pragma unroll
    for (int i = 0; i < 4; ++i) v[i] = (base + i < nb) ? g_blk[base + i] : 0;
    int tsum = v[0] + v[1] + v[2] + v[3];
    sh[tid] = tsum;
    __syncthreads();
    for (int off = 1; off < 256; off <<= 1) {
        int t = (tid >= off) ? sh[tid - off] : 0;
        __syncthreads();
        sh[tid] += t;
        __syncthreads();
    }
    int run = sh[tid] - tsum;
#pragma unroll
    for (int i = 0; i < 4; ++i) {
        if (base + i < nb) g_blk[base + i] = run;
        run += v[i];
    }
}

__global__ void scan3_kernel(int n) {
    int off = g_blk[blockIdx.x];
    int base = blockIdx.x * SCAN_TILE + threadIdx.x * 4;
#pragma unroll
    for (int i = 0; i < 4; ++i) {
        int idx = base + i;
        if (idx < n) g_part[idx] += off;
    }
}

// Re-reads the IDENTICAL edge range as hist_deg_kernel; per-bin LDS cursors start
// at the scanned (bin,block) offsets, so record placement needs no global atomics.
__global__ __launch_bounds__(256) void scatter_kernel(const int* __restrict__ ei,
                                                      const float* __restrict__ w,
                                                      int E, int n_nodes, int nbuck,
                                                      int per_blk) {
    __shared__ int cur[MAX_NB];
    for (int i = threadIdx.x; i < nbuck; i += 256)
        cur[i] = g_part[i * NBLK + blockIdx.x];
    __syncthreads();
    int start = blockIdx.x * per_blk;
    int end = start + per_blk;
    if (end > E) end = E;
    for (int e = start + threadIdx.x; e < end; e += 256) {
        int s = ei[e];
        int d = ei[E + e];
        if ((unsigned)s >= (unsigned)n_nodes || (unsigned)d >= (unsigned)n_nodes) continue;
        float nrm = (s == d) ? 0.f : -g_deg[s] * w[e] * g_deg[d];  // g_deg holds dinv
        int pos = atomicAdd(&cur[d >> CBSH], 1);                   // LDS atomic
        g_rec[pos] = make_uint2(((unsigned)s << CBSH) | (unsigned)(d & (CB - 1)),
                                __float_as_uint(nrm));
    }
}

// One block per 64-node bucket: accumulate tx1 rows in an 8 KB LDS tile with
// ds_add_f32 (lane f -> bank f; 2 lanes/bank across the wave = free), coalesced
// write-out. Pipeline: each wave owns a contiguous chunk; main loop consumes
// exactly 16 records per iteration (8 per half-wave) with NAMED scalar payload
// and ZERO guards in the body -> 8 independent rec loads, then 8 independent
// x-row loads, then 8 LDS atomics. Divergent scalar tail handles the <16 rest.
__global__ __launch_bounds__(256) void bucket_gather_kernel(const float* __restrict__ x,
                                                            int n_nodes, int nbuck) {
    __shared__ float acc[CB * FDIM];   // 8 KB
    int b = blockIdx.x;
    for (int i = threadIdx.x; i < CB * FDIM; i += 256) acc[i] = 0.f;
    int rs = g_part[b * NBLK];
    int re = g_part[(b + 1) * NBLK];   // b == nbuck-1 hits the sentinel (= total)
    __syncthreads();

    int wid  = __builtin_amdgcn_readfirstlane(threadIdx.x >> 6);  // 0..3, SGPR
    int half = (threadIdx.x >> 5) & 1;   // which record of each pair
    int f    = threadIdx.x & 31;

    int total = re - rs;
    int chunk = (total + 3) >> 2;        // per-wave contiguous range
    int wbeg = rs + wid * chunk;
    int wend = wbeg + chunk; if (wend > re) wend = re;

    int i0 = wbeg;
    for (; i0 + 16 <= wend; i0 += 16) {
        int j = i0 + half;
        uint2 r0 = g_rec[j];
        uint2 r1 = g_rec[j + 2];
        uint2 r2 = g_rec[j + 4];
        uint2 r3 = g_rec[j + 6];
        uint2 r4 = g_rec[j + 8];
        uint2 r5 = g_rec[j + 10];
        uint2 r6 = g_rec[j + 12];
        uint2 r7 = g_rec[j + 14];
        float x0 = x[(r0.x >> CBSH) * FDIM + f];
        float x1 = x[(r1.x >> CBSH) * FDIM + f];
        float x2 = x[(r2.x >> CBSH) * FDIM + f];
        float x3 = x[(r3.x >> CBSH) * FDIM + f];
        float x4 = x[(r4.x >> CBSH) * FDIM + f];
        float x5 = x[(r5.x >> CBSH) * FDIM + f];
        float x6 = x[(r6.x >> CBSH) * FDIM + f];
        float x7 = x[(r7.x >> CBSH) * FDIM + f];
        atomicAdd(&acc[(r0.x & (CB - 1)) * FDIM + f], __uint_as_float(r0.y) * x0);
        atomicAdd(&acc[(r1.x & (CB - 1)) * FDIM + f], __uint_as_float(r1.y) * x1);
        atomicAdd(&acc[(r2.x & (CB - 1)) * FDIM + f], __uint_as_float(r2.y) * x2);
        atomicAdd(&acc[(r3.x & (CB - 1)) * FDIM + f], __uint_as_float(r3.y) * x3);
        atomicAdd(&acc[(r4.x & (CB - 1)) * FDIM + f], __uint_as_float(r4.y) * x4);
        atomicAdd(&acc[(r5.x & (CB - 1)) * FDIM + f], __uint_as_float(r5.y) * x5);
        atomicAdd(&acc[(r6.x & (CB - 1)) * FDIM + f], __uint_as_float(r6.y) * x6);
        atomicAdd(&acc[(r7.x & (CB - 1)) * FDIM + f], __uint_as_float(r7.y) * x7);
    }
    for (int j = i0 + half; j < wend; j += 2) {   // tail: < 16 records
        uint2 r = g_rec[j];
        float xv = x[(r.x >> CBSH) * FDIM + f];
        atomicAdd(&acc[(r.x & (CB - 1)) * FDIM + f], __uint_as_float(r.y) * xv);
    }
    __syncthreads();
    int base = b << CBSH;
    for (int row = threadIdx.x >> 5; row < CB; row += 8) {
        int n = base + row;
        if (n < n_nodes) g_tx1[n * FDIM + f] = acc[row * FDIM + f];
    }
}

// 8 nodes per 256-thread block; thread (node, j) computes output feature j of
// gates i, c, o. Weights for the 3 live gates staged in LDS (24 KB).
__global__ __launch_bounds__(256) void gates_kernel(
    const float* __restrict__ x,
    const float* __restrict__ Wx, const float* __restrict__ bx,
    const float* __restrict__ bh, const float* __restrict__ wc,
    const float* __restrict__ bg, const float* __restrict__ lin_w,
    const float* __restrict__ lin_b, float* __restrict__ out, int n_nodes) {
    __shared__ float Ws[3 * 2048];      // gates {i,c,o} x K=2 x 32x32
    __shared__ float xs[8 * FDIM];
    __shared__ float ts[8 * FDIM];

    for (int idx = threadIdx.x; idx < 2048; idx += 256) {
        Ws[idx]          = Wx[0 * 2048 + idx];
        Ws[2048 + idx]   = Wx[2 * 2048 + idx];
        Ws[4096 + idx]   = Wx[3 * 2048 + idx];
    }
    int node0 = blockIdx.x * 8;
    {
        int n = node0 + (threadIdx.x >> 5);
        int f = threadIdx.x & 31;
        if (n < n_nodes) {
            xs[threadIdx.x] = x[n * FDIM + f];
            ts[threadIdx.x] = g_tx1[n * FDIM + f];
        }
    }
    __syncthreads();

    int ln = threadIdx.x >> 5;
    int j  = threadIdx.x & 31;
    int n  = node0 + ln;
    if (n >= n_nodes) return;

    const float* xr = &xs[ln * FDIM];
    const float* tr = &ts[ln * FDIM];
    float acc_i = 0.f, acc_c = 0.f, acc_o = 0.f;
#pragma unroll
    for (int k = 0; k < 32; ++k) {
        float xv = xr[k], tv = tr[k];
        int o0 = k * 32 + j;
        acc_i += xv * Ws[o0]          + tv * Ws[1024 + o0];
        acc_c += xv * Ws[2048 + o0]   + tv * Ws[3072 + o0];
        acc_o += xv * Ws[4096 + o0]   + tv * Ws[5120 + o0];
    }
    float bi = bx[0 * 32 + j] + bh[0 * 32 + j] + bg[0 * 32 + j];
    float bc = bx[2 * 32 + j] + bh[2 * 32 + j] + bg[2 * 32 + j];
    float bo = bx[3 * 32 + j] + bh[3 * 32 + j] + bg[3 * 32 + j];

    float I = 1.f / (1.f + __expf(-(acc_i + bi)));
    float T = tanhf(acc_c + bc);
    float C = I * T;                                    // Fg*C_prev = 0
    float O = 1.f / (1.f + __expf(-(acc_o + bo + wc[2 * 32 + j] * C)));
    float H = O * tanhf(C);
    float r = fmaxf(H, 0.f) * lin_w[j];
#pragma unroll
    for (int m = 16; m > 0; m >>= 1) r += __shfl_xor(r, m, 32);
    if (j == 0) out[n] = r + lin_b[0];
}

extern "C" void kernel_launch(void* const* d_in, const int* in_sizes, int n_in,
                              void* d_out, int out_size, void* d_ws, size_t ws_size,
                              hipStream_t stream) {
    const float* x     = (const float*)d_in[0];
    const int*   ei    = (const int*)d_in[1];      // int32 on device
    const float* w     = (const float*)d_in[2];
    const float* Wx    = (const float*)d_in[3];
    const float* bx    = (const float*)d_in[4];
    // d_in[5] = Wh: unused (H=0)
    const float* bh    = (const float*)d_in[6];
    const float* wc    = (const float*)d_in[7];
    const float* bg    = (const float*)d_in[8];
    const float* lin_w = (const float*)d_in[9];
    const float* lin_b = (const float*)d_in[10];
    float*       out   = (float*)d_out;

    int n_nodes = in_sizes[0] / FDIM;
    if (n_nodes > MAX_N) n_nodes = MAX_N;
    int E = in_sizes[2];
    if (E > MAX_E) E = MAX_E;

    int nbuck   = (n_nodes + CB - 1) >> CBSH;            // 1563 for N=100k
    int per_blk = (E + NBLK - 1) / NBLK;                 // 3125 edges/block
    int n_scan  = nbuck * NBLK + 1;                      // 800257
    int nb_scan = (n_scan + SCAN_TILE - 1) / SCAN_TILE;  // 782 (<= 1024 for scan2)

    zero_kernel<<<512, 256, 0, stream>>>(n_nodes, nbuck);
    hist_deg_kernel<<<NBLK, 256, 0, stream>>>(ei, w, E, n_nodes, nbuck, per_blk);
    dinv_kernel<<<(n_nodes + 255) / 256, 256, 0, stream>>>(n_nodes);
    scan1_kernel<<<nb_scan, 256, 0, stream>>>(n_scan);
    scan2_kernel<<<1, 256, 0, stream>>>(nb_scan);
    scan3_kernel<<<nb_scan, 256, 0, stream>>>(n_scan);
    scatter_kernel<<<NBLK, 256, 0, stream>>>(ei, w, E, n_nodes, nbuck, per_blk);
    bucket_gather_kernel<<<nbuck, 256, 0, stream>>>(x, n_nodes, nbuck);
    gates_kernel<<<(n_nodes + 7) / 8, 256, 0, stream>>>(
        x, Wx, bx, bh, wc, bg, lin_w, lin_b, out, n_nodes);
}